// Round 14
// baseline (123.921 us; speedup 1.0000x reference)
//
#include <hip/hip_runtime.h>

// G=16, H=8, N=128/side, HD=32, D=256
// x tensors: row-major [2048][256] f32; head (g,h) chunk = flat gh*4096, node-major [128][32].
#define C2L2E 2.8853900817779268f   // 2*log2(e)
#define LOG2E 1.4426950408889634f

// ws float offsets
#define WS_X1   0          // [2048][256] f32 x1
#define WS_X2   524288     // [2048][256] f32 x2
#define WS_RS   1048576    // [gh][128] row sums
#define WS_CQ   1064960    // [gh*4+qd][128] col quarter partials

typedef short bf16x8 __attribute__((ext_vector_type(8)));
typedef float f32x4 __attribute__((ext_vector_type(4)));

__device__ __forceinline__ unsigned short bf16rne(float f) {
    unsigned u = __float_as_uint(f);
    u += 0x7FFF + ((u >> 16) & 1);
    return (unsigned short)(u >> 16);
}
__device__ __forceinline__ float bf16tof(unsigned short h) {
    return __uint_as_float(((unsigned)h) << 16);
}
// bit-preserving wave-uniform scalar broadcast (readfirstlane is int-typed!)
__device__ __forceinline__ float rfl(float x) {
    return __uint_as_float(__builtin_amdgcn_readfirstlane(__float_as_uint(x)));
}
// convert 8 f32 (two float4) -> bf16 hi + lo fragments
__device__ __forceinline__ void cvt8(float4 v0, float4 v1, bf16x8* hi, bf16x8* lo) {
    unsigned short h[8], l[8];
    float f[8] = {v0.x, v0.y, v0.z, v0.w, v1.x, v1.y, v1.z, v1.w};
    #pragma unroll
    for (int e = 0; e < 8; ++e) {
        h[e] = bf16rne(f[e]);
        l[e] = bf16rne(f[e] - bf16tof(h[e]));
    }
    #pragma unroll
    for (int e = 0; e < 8; ++e) { (*hi)[e] = (short)h[e]; (*lo)[e] = (short)l[e]; }
}

// ================= K01: fused convert + split-bf16 MFMA GEMM x = In @ W^T + bias =================
// grid 256: mat=bid>>7; idx=bid&127 -> r0=(idx>>2)*64, c0=(idx&3)*64. 4 waves, wave = 16-row tile.
// Each thread loads its OWN fragment elements (k0's verified row/col mapping) straight from
// f32 global, converts in registers, MFMAs. No staging kernel, no LDS.
// A frag: row=lane&15, k=(lane>>4)*8+e ; B(W) frag: col=lane&15, same k (verified r8).
__global__ __launch_bounds__(256) void k01_gemm(
        const float* __restrict__ A, const float* __restrict__ B,
        const float* __restrict__ W1, const float* __restrict__ b1,
        const float* __restrict__ W2, const float* __restrict__ b2,
        float* __restrict__ ws) {
    const int bid = blockIdx.x, tid = threadIdx.x;
    const int mat = bid >> 7, idx = bid & 127;
    const int r0 = (idx >> 2) * 64, c0 = (idx & 3) * 64;
    const float* In = mat ? B : A;
    const float* Wm = mat ? W2 : W1;
    const float* bs = mat ? b2 : b1;
    float* xo = ws + (mat ? WS_X2 : WS_X1);

    const int wv = tid >> 6, lane = tid & 63;
    const int l16 = lane & 15, kbase = (lane >> 4) * 8;
    const int arow = r0 + wv * 16 + l16;

    // preload + convert this thread's A fragments for all 8 k-tiles
    bf16x8 ah[8], al[8];
    #pragma unroll
    for (int kt = 0; kt < 8; ++kt) {
        const float* p = In + (size_t)arow * 256 + kt * 32 + kbase;
        cvt8(*(const float4*)p, *(const float4*)(p + 4), &ah[kt], &al[kt]);
    }

    f32x4 acc[4];
    #pragma unroll
    for (int nt = 0; nt < 4; ++nt) acc[nt] = (f32x4){0.f, 0.f, 0.f, 0.f};

    #pragma unroll 2
    for (int kt = 0; kt < 8; ++kt) {
        #pragma unroll
        for (int nt = 0; nt < 4; ++nt) {
            const int wcol = c0 + nt * 16 + l16;
            const float* p = Wm + (size_t)wcol * 256 + kt * 32 + kbase;
            bf16x8 wh, wl;
            cvt8(*(const float4*)p, *(const float4*)(p + 4), &wh, &wl);
            acc[nt] = __builtin_amdgcn_mfma_f32_16x16x32_bf16(ah[kt], wh, acc[nt], 0, 0, 0);
            acc[nt] = __builtin_amdgcn_mfma_f32_16x16x32_bf16(ah[kt], wl, acc[nt], 0, 0, 0);
            acc[nt] = __builtin_amdgcn_mfma_f32_16x16x32_bf16(al[kt], wh, acc[nt], 0, 0, 0);
        }
    }

    const int rowb = r0 + wv * 16 + (lane >> 4) * 4;   // C/D: row=(lane>>4)*4+reg, col=lane&15
    #pragma unroll
    for (int nt = 0; nt < 4; ++nt) {
        const int col = c0 + nt * 16 + l16;
        const float bb = bs[col];
        #pragma unroll
        for (int rg = 0; rg < 4; ++rg)
            xo[(size_t)(rowb + rg) * 256 + col] = acc[nt][rg] + bb;
    }
}

// ================= K2: S-sums of q·tanh(x1*x2) — exp2 form, SGPR a/qt (r12-verified) =================
// S = sum_k (-2q_k)/(t+1), t = exp2(xr_scaled * a), xr pre-scaled by 2log2e (r9/r10-verified math).
__global__ __launch_bounds__(512, 6) void k2_att(
        const float* __restrict__ x1v, const float* __restrict__ x2v,
        const float* __restrict__ q,
        float* __restrict__ rowsum, float* __restrict__ colq) {
    const int bid = blockIdx.x;
    const int gh = bid >> 2;
    const int qd = bid & 3;
    const int tid = threadIdx.x;
    const int j = tid & 127;
    const int iset = __builtin_amdgcn_readfirstlane(tid >> 7);  // wave-uniform 0..3

    __shared__ float Smat[32 * 132];
    __shared__ float colp[4][128];
    __shared__ float red8[32][8];

    // x2 row j -> VGPRs, pre-scaled by 2log2e
    float xr[32];
    {
        const float4* xp = (const float4*)(x2v + (size_t)gh * 4096 + (size_t)j * 32);
        #pragma unroll
        for (int k4 = 0; k4 < 8; ++k4) {
            float4 v = xp[k4];
            xr[k4*4+0] = v.x * C2L2E; xr[k4*4+1] = v.y * C2L2E;
            xr[k4*4+2] = v.z * C2L2E; xr[k4*4+3] = v.w * C2L2E;
        }
    }
    // qt = -2q -> SGPRs (bit-preserving broadcast)
    float qt[32];
    #pragma unroll
    for (int k4 = 0; k4 < 8; ++k4) {
        float4 v = *(const float4*)(q + k4 * 4);
        qt[k4*4+0] = rfl(v.x) * -2.0f;
        qt[k4*4+1] = rfl(v.y) * -2.0f;
        qt[k4*4+2] = rfl(v.z) * -2.0f;
        qt[k4*4+3] = rfl(v.w) * -2.0f;
    }

    const float* x1base = x1v + (size_t)gh * 4096 + (size_t)(qd * 32 + iset * 8) * 32;
    float colacc = 0.f;

    for (int r = 0; r < 8; ++r) {
        float a[32];                                   // wave-uniform -> SGPRs
        #pragma unroll
        for (int k4 = 0; k4 < 8; ++k4) {
            float4 v = *(const float4*)(x1base + r * 32 + k4 * 4);
            a[k4*4+0] = rfl(v.x);
            a[k4*4+1] = rfl(v.y);
            a[k4*4+2] = rfl(v.z);
            a[k4*4+3] = rfl(v.w);
        }
        float S0 = 0.f, S1 = 0.f;
        #pragma unroll
        for (int kp = 0; kp < 16; ++kp) {
            float p0 = a[2*kp]   * xr[2*kp];
            float p1 = a[2*kp+1] * xr[2*kp+1];
            float d0 = __builtin_amdgcn_exp2f(fminf(p0, 60.f)) + 1.f;
            float d1 = __builtin_amdgcn_exp2f(fminf(p1, 60.f)) + 1.f;
            float rD = __builtin_amdgcn_rcpf(d0 * d1);
            float U  = fmaf(qt[2*kp+1], d0, qt[2*kp] * d1);
            if (kp & 1) S1 = fmaf(U, rD, S1); else S0 = fmaf(U, rD, S0);
        }
        float S = S0 + S1;
        colacc += S;
        Smat[(iset * 8 + r) * 132 + j] = S;
    }
    colp[iset][j] = colacc;
    __syncthreads();

    if (tid < 256) {                       // rowsum stage 1: 16-chunk sums
        const int row = tid >> 3, seg = tid & 7;
        const float4* sp = (const float4*)(Smat + row * 132 + seg * 16);
        float4 v0 = sp[0], v1 = sp[1], v2 = sp[2], v3 = sp[3];
        red8[row][seg] = (v0.x+v0.y+v0.z+v0.w) + (v1.x+v1.y+v1.z+v1.w)
                       + (v2.x+v2.y+v2.z+v2.w) + (v3.x+v3.y+v3.z+v3.w);
    }
    __syncthreads();
    if (tid < 32) {
        float s = 0.f;
        #pragma unroll
        for (int m = 0; m < 8; ++m) s += red8[tid][m];
        rowsum[gh * 128 + qd * 32 + tid] = s;
    }
    if (tid < 128) {
        colq[(size_t)bid * 128 + tid] =
            colp[0][tid] + colp[1][tid] + colp[2][tid] + colp[3][tid];
    }
}

// ================= K3: softmaxes + weighted sums -> out (verified) =================
__global__ __launch_bounds__(256) void k3_out(
        const float* __restrict__ x1v, const float* __restrict__ x2v,
        const float* __restrict__ rowsum, const float* __restrict__ colq,
        float* __restrict__ out) {
    const int gh = blockIdx.x;
    const int g = gh >> 3, h = gh & 7;
    const int tid = threadIdx.x;
    const int side = tid >> 7;
    const int u = tid & 127;
    const int w2 = (u >> 6) & 1;
    const int lane = tid & 63;

    __shared__ float warr[2][128];
    __shared__ float red[4];
    __shared__ float red2[4];
    __shared__ float part[2][4][32];

    float m;
    if (side == 0) {
        m = rowsum[gh * 128 + u] * 0.0078125f;
    } else {
        m = (colq[(size_t)(gh * 4 + 0) * 128 + u] + colq[(size_t)(gh * 4 + 1) * 128 + u] +
             colq[(size_t)(gh * 4 + 2) * 128 + u] + colq[(size_t)(gh * 4 + 3) * 128 + u]) * 0.0078125f;
    }

    float mx = m;
    #pragma unroll
    for (int s = 32; s >= 1; s >>= 1) mx = fmaxf(mx, __shfl_xor(mx, s));
    if (lane == 0) red[side * 2 + w2] = mx;
    __syncthreads();
    mx = fmaxf(red[side * 2], red[side * 2 + 1]);

    float e = __builtin_amdgcn_exp2f((m - mx) * LOG2E);
    float sm = e;
    #pragma unroll
    for (int s = 32; s >= 1; s >>= 1) sm += __shfl_xor(sm, s);
    if (lane == 0) red2[side * 2 + w2] = sm;
    __syncthreads();
    const float tot = red2[side * 2] + red2[side * 2 + 1];
    warr[side][u] = e * __builtin_amdgcn_rcpf(tot);
    __syncthreads();

    const int k = u & 31, is = u >> 5;
    const float* xt = (side ? x2v : x1v) + (size_t)gh * 4096;
    float p = 0.f;
    #pragma unroll 4
    for (int r = 0; r < 32; ++r)
        p = fmaf(xt[(is * 32 + r) * 32 + k], warr[side][is * 32 + r], p);
    part[side][is][k] = p;
    __syncthreads();
    if (u < 32) {
        float o = part[side][0][u] + part[side][1][u] + part[side][2][u] + part[side][3][u];
        out[(size_t)g * 512 + side * 256 + h * 32 + u] = o;
    }
}

extern "C" void kernel_launch(void* const* d_in, const int* in_sizes, int n_in,
                              void* d_out, int out_size, void* d_ws, size_t ws_size,
                              hipStream_t stream) {
    const float* A  = (const float*)d_in[0];
    const float* B  = (const float*)d_in[2];
    const float* W1 = (const float*)d_in[4];
    const float* b1 = (const float*)d_in[5];
    const float* W2 = (const float*)d_in[6];
    const float* b2 = (const float*)d_in[7];
    const float* q  = (const float*)d_in[8];
    float* ws  = (float*)d_ws;
    float* out = (float*)d_out;

    k01_gemm<<<256, 256, 0, stream>>>(A, B, W1, b1, W2, b2, ws);
    k2_att<<<512, 512, 0, stream>>>(ws + WS_X1, ws + WS_X2, q, ws + WS_RS, ws + WS_CQ);
    k3_out<<<128, 256, 0, stream>>>(ws + WS_X1, ws + WS_X2, ws + WS_RS, ws + WS_CQ, out);
}

// Round 15
// 37.330 us; speedup vs baseline: 3.3196x; 3.3196x over previous
//
#include <hip/hip_runtime.h>

// G=16, H=8, N=128/side, HD=32, D=256
// x tensors: row-major [2048][256] f32; head (g,h) chunk = flat gh*4096, node-major [128][32].
#define C2L2E 2.8853900817779268f   // 2*log2(e)
#define LOG2E 1.4426950408889634f

// ws float offsets
#define WS_X1   0          // [2048][256] f32 x1
#define WS_X2   524288     // [2048][256] f32 x2
#define WS_RS   1048576    // [gh][128] row sums
#define WS_CQ   1064960    // [gh*4+qd][128] col quarter partials

typedef short bf16x8 __attribute__((ext_vector_type(8)));
typedef float f32x4 __attribute__((ext_vector_type(4)));

__device__ __forceinline__ unsigned short bf16rne(float f) {
    unsigned u = __float_as_uint(f);
    u += 0x7FFF + ((u >> 16) & 1);
    return (unsigned short)(u >> 16);
}
__device__ __forceinline__ float bf16tof(unsigned short h) {
    return __uint_as_float(((unsigned)h) << 16);
}
// bit-preserving wave-uniform scalar broadcast (readfirstlane is int-typed!)
__device__ __forceinline__ float rfl(float x) {
    return __uint_as_float(__builtin_amdgcn_readfirstlane(__float_as_uint(x)));
}
__device__ __forceinline__ void cvt4(float4 v, ushort4* h, ushort4* l) {
    h->x = bf16rne(v.x); l->x = bf16rne(v.x - bf16tof(h->x));
    h->y = bf16rne(v.y); l->y = bf16rne(v.y - bf16tof(h->y));
    h->z = bf16rne(v.z); l->z = bf16rne(v.z - bf16tof(h->z));
    h->w = bf16rne(v.w); l->w = bf16rne(v.w - bf16tof(h->w));
}

// ================= K01: fused LDS-staged convert + split-bf16 MFMA GEMM =================
// grid 256: mat=bid>>7; idx=bid&127 -> r0=(idx>>2)*64 (A rows), c0=(idx&3)*64 (W cols).
// 512 threads = 8 waves. Per k-tile (32 k): COALESCED f32 loads of A[64x32]/W[64x32],
// in-register bf16 hi/lo convert, LDS write in verified fragment layout
// (frag[rt][lane][e] = Src[rt*16+(lane&15)][kt*32+(lane>>4)*8+e], verified r8/r9),
// then lane-contiguous ds_read_b128 fragments -> MFMA.
// Wave wv: A row-tile rt=wv&3; col-tiles nt0=(wv>>2)*2 .. +1.
__global__ __launch_bounds__(512) void k01_gemm(
        const float* __restrict__ A, const float* __restrict__ B,
        const float* __restrict__ W1, const float* __restrict__ b1,
        const float* __restrict__ W2, const float* __restrict__ b2,
        float* __restrict__ ws) {
    __shared__ unsigned short AH[2048], AL[2048], WH[2048], WL[2048];  // 4 x 4KB
    const int bid = blockIdx.x, tid = threadIdx.x;
    const int mat = bid >> 7, idx = bid & 127;
    const int r0 = (idx >> 2) * 64, c0 = (idx & 3) * 64;
    const float* In = mat ? B : A;
    const float* Wm = mat ? W2 : W1;
    const float* bs = mat ? b2 : b1;
    float* xo = ws + (mat ? WS_X2 : WS_X1);

    const int wv = tid >> 6, lane = tid & 63;
    const int rt = wv & 3;              // A row-tile for this wave
    const int nt0 = (wv >> 2) * 2;      // first col-tile for this wave

    // loader mapping: thread t stages row lr = t>>3, k-quad k4 = t&7 (verified algebra)
    const int lr = tid >> 3, k4 = tid & 7;
    const int wofs = (((lr >> 4) * 64 + (lr & 15) + ((k4 >> 1) << 4)) * 8 + (k4 & 1) * 4);

    f32x4 acc[2];
    acc[0] = (f32x4){0.f, 0.f, 0.f, 0.f};
    acc[1] = (f32x4){0.f, 0.f, 0.f, 0.f};

    for (int kt = 0; kt < 8; ++kt) {
        if (kt) __syncthreads();        // previous tile fully consumed
        {   // stage A + W (coalesced float4 global loads)
            float4 va = *(const float4*)(In + (size_t)(r0 + lr) * 256 + kt * 32 + k4 * 4);
            ushort4 h, l; cvt4(va, &h, &l);
            *(ushort4*)(AH + wofs) = h;
            *(ushort4*)(AL + wofs) = l;
            float4 vw = *(const float4*)(Wm + (size_t)(c0 + lr) * 256 + kt * 32 + k4 * 4);
            cvt4(vw, &h, &l);
            *(ushort4*)(WH + wofs) = h;
            *(ushort4*)(WL + wofs) = l;
        }
        __syncthreads();
        {   // consume: lane-contiguous 16B fragment reads
            bf16x8 ah = *(const bf16x8*)(AH + (rt * 64 + lane) * 8);
            bf16x8 al = *(const bf16x8*)(AL + (rt * 64 + lane) * 8);
            #pragma unroll
            for (int nt = 0; nt < 2; ++nt) {
                const int ct = nt0 + nt;
                bf16x8 wh = *(const bf16x8*)(WH + (ct * 64 + lane) * 8);
                bf16x8 wl = *(const bf16x8*)(WL + (ct * 64 + lane) * 8);
                acc[nt] = __builtin_amdgcn_mfma_f32_16x16x32_bf16(ah, wh, acc[nt], 0, 0, 0);
                acc[nt] = __builtin_amdgcn_mfma_f32_16x16x32_bf16(ah, wl, acc[nt], 0, 0, 0);
                acc[nt] = __builtin_amdgcn_mfma_f32_16x16x32_bf16(al, wh, acc[nt], 0, 0, 0);
            }
        }
    }

    // epilogue: C/D row=(lane>>4)*4+reg, col=lane&15 (verified r8)
    const int rowb = r0 + rt * 16 + (lane >> 4) * 4;
    const int l16 = lane & 15;
    #pragma unroll
    for (int nt = 0; nt < 2; ++nt) {
        const int col = c0 + (nt0 + nt) * 16 + l16;
        const float bb = bs[col];
        #pragma unroll
        for (int rg = 0; rg < 4; ++rg)
            xo[(size_t)(rowb + rg) * 256 + col] = acc[nt][rg] + bb;
    }
}

// ================= K2: S-sums of q·tanh(x1*x2) — exp2 form, SGPR a/qt (r14-verified) =================
__global__ __launch_bounds__(512, 6) void k2_att(
        const float* __restrict__ x1v, const float* __restrict__ x2v,
        const float* __restrict__ q,
        float* __restrict__ rowsum, float* __restrict__ colq) {
    const int bid = blockIdx.x;
    const int gh = bid >> 2;
    const int qd = bid & 3;
    const int tid = threadIdx.x;
    const int j = tid & 127;
    const int iset = __builtin_amdgcn_readfirstlane(tid >> 7);  // wave-uniform 0..3

    __shared__ float Smat[32 * 132];
    __shared__ float colp[4][128];
    __shared__ float red8[32][8];

    // x2 row j -> VGPRs, pre-scaled by 2log2e
    float xr[32];
    {
        const float4* xp = (const float4*)(x2v + (size_t)gh * 4096 + (size_t)j * 32);
        #pragma unroll
        for (int k4 = 0; k4 < 8; ++k4) {
            float4 v = xp[k4];
            xr[k4*4+0] = v.x * C2L2E; xr[k4*4+1] = v.y * C2L2E;
            xr[k4*4+2] = v.z * C2L2E; xr[k4*4+3] = v.w * C2L2E;
        }
    }
    // qt = -2q -> SGPRs (bit-preserving broadcast)
    float qt[32];
    #pragma unroll
    for (int k4 = 0; k4 < 8; ++k4) {
        float4 v = *(const float4*)(q + k4 * 4);
        qt[k4*4+0] = rfl(v.x) * -2.0f;
        qt[k4*4+1] = rfl(v.y) * -2.0f;
        qt[k4*4+2] = rfl(v.z) * -2.0f;
        qt[k4*4+3] = rfl(v.w) * -2.0f;
    }

    const float* x1base = x1v + (size_t)gh * 4096 + (size_t)(qd * 32 + iset * 8) * 32;
    float colacc = 0.f;

    for (int r = 0; r < 8; ++r) {
        float a[32];                                   // wave-uniform -> SGPRs
        #pragma unroll
        for (int k4 = 0; k4 < 8; ++k4) {
            float4 v = *(const float4*)(x1base + r * 32 + k4 * 4);
            a[k4*4+0] = rfl(v.x);
            a[k4*4+1] = rfl(v.y);
            a[k4*4+2] = rfl(v.z);
            a[k4*4+3] = rfl(v.w);
        }
        float S0 = 0.f, S1 = 0.f;
        #pragma unroll
        for (int kp = 0; kp < 16; ++kp) {
            float p0 = a[2*kp]   * xr[2*kp];
            float p1 = a[2*kp+1] * xr[2*kp+1];
            float d0 = __builtin_amdgcn_exp2f(fminf(p0, 60.f)) + 1.f;
            float d1 = __builtin_amdgcn_exp2f(fminf(p1, 60.f)) + 1.f;
            float rD = __builtin_amdgcn_rcpf(d0 * d1);
            float U  = fmaf(qt[2*kp+1], d0, qt[2*kp] * d1);
            if (kp & 1) S1 = fmaf(U, rD, S1); else S0 = fmaf(U, rD, S0);
        }
        float S = S0 + S1;
        colacc += S;
        Smat[(iset * 8 + r) * 132 + j] = S;
    }
    colp[iset][j] = colacc;
    __syncthreads();

    if (tid < 256) {                       // rowsum stage 1: 16-chunk sums
        const int row = tid >> 3, seg = tid & 7;
        const float4* sp = (const float4*)(Smat + row * 132 + seg * 16);
        float4 v0 = sp[0], v1 = sp[1], v2 = sp[2], v3 = sp[3];
        red8[row][seg] = (v0.x+v0.y+v0.z+v0.w) + (v1.x+v1.y+v1.z+v1.w)
                       + (v2.x+v2.y+v2.z+v2.w) + (v3.x+v3.y+v3.z+v3.w);
    }
    __syncthreads();
    if (tid < 32) {
        float s = 0.f;
        #pragma unroll
        for (int m = 0; m < 8; ++m) s += red8[tid][m];
        rowsum[gh * 128 + qd * 32 + tid] = s;
    }
    if (tid < 128) {
        colq[(size_t)bid * 128 + tid] =
            colp[0][tid] + colp[1][tid] + colp[2][tid] + colp[3][tid];
    }
}

// ================= K3: softmaxes + weighted sums -> out (verified) =================
__global__ __launch_bounds__(256) void k3_out(
        const float* __restrict__ x1v, const float* __restrict__ x2v,
        const float* __restrict__ rowsum, const float* __restrict__ colq,
        float* __restrict__ out) {
    const int gh = blockIdx.x;
    const int g = gh >> 3, h = gh & 7;
    const int tid = threadIdx.x;
    const int side = tid >> 7;
    const int u = tid & 127;
    const int w2 = (u >> 6) & 1;
    const int lane = tid & 63;

    __shared__ float warr[2][128];
    __shared__ float red[4];
    __shared__ float red2[4];
    __shared__ float part[2][4][32];

    float m;
    if (side == 0) {
        m = rowsum[gh * 128 + u] * 0.0078125f;
    } else {
        m = (colq[(size_t)(gh * 4 + 0) * 128 + u] + colq[(size_t)(gh * 4 + 1) * 128 + u] +
             colq[(size_t)(gh * 4 + 2) * 128 + u] + colq[(size_t)(gh * 4 + 3) * 128 + u]) * 0.0078125f;
    }

    float mx = m;
    #pragma unroll
    for (int s = 32; s >= 1; s >>= 1) mx = fmaxf(mx, __shfl_xor(mx, s));
    if (lane == 0) red[side * 2 + w2] = mx;
    __syncthreads();
    mx = fmaxf(red[side * 2], red[side * 2 + 1]);

    float e = __builtin_amdgcn_exp2f((m - mx) * LOG2E);
    float sm = e;
    #pragma unroll
    for (int s = 32; s >= 1; s >>= 1) sm += __shfl_xor(sm, s);
    if (lane == 0) red2[side * 2 + w2] = sm;
    __syncthreads();
    const float tot = red2[side * 2] + red2[side * 2 + 1];
    warr[side][u] = e * __builtin_amdgcn_rcpf(tot);
    __syncthreads();

    const int k = u & 31, is = u >> 5;
    const float* xt = (side ? x2v : x1v) + (size_t)gh * 4096;
    float p = 0.f;
    #pragma unroll 4
    for (int r = 0; r < 32; ++r)
        p = fmaf(xt[(is * 32 + r) * 32 + k], warr[side][is * 32 + r], p);
    part[side][is][k] = p;
    __syncthreads();
    if (u < 32) {
        float o = part[side][0][u] + part[side][1][u] + part[side][2][u] + part[side][3][u];
        out[(size_t)g * 512 + side * 256 + h * 32 + u] = o;
    }
}

extern "C" void kernel_launch(void* const* d_in, const int* in_sizes, int n_in,
                              void* d_out, int out_size, void* d_ws, size_t ws_size,
                              hipStream_t stream) {
    const float* A  = (const float*)d_in[0];
    const float* B  = (const float*)d_in[2];
    const float* W1 = (const float*)d_in[4];
    const float* b1 = (const float*)d_in[5];
    const float* W2 = (const float*)d_in[6];
    const float* b2 = (const float*)d_in[7];
    const float* q  = (const float*)d_in[8];
    float* ws  = (float*)d_ws;
    float* out = (float*)d_out;

    k01_gemm<<<256, 512, 0, stream>>>(A, B, W1, b1, W2, b2, ws);
    k2_att<<<512, 512, 0, stream>>>(ws + WS_X1, ws + WS_X2, q, ws + WS_RS, ws + WS_CQ);
    k3_out<<<128, 256, 0, stream>>>(ws + WS_X1, ws + WS_X2, ws + WS_RS, ws + WS_CQ, out);
}